// Round 2
// baseline (423.728 us; speedup 1.0000x reference)
//
#include <hip/hip_runtime.h>
#include <cstdint>
#include <cstddef>

#define N_B 128
#define N_I 784
#define N_H 410
#define N_O 10
#define TT  300
#define KL  64
#define NK  832         // K-padded input features (13 * 64)
#define NKS 13          // layer-1 K-steps of 64 (832)
#define NTILES 26       // layer-1 N-tiles of 16 (410 -> 416)
#define NDIG 4          // base-256 digits of round(W * 2^28)
#define NKS2 7          // layer-2 K-steps of 64 (448)
#define S1_TILE 4800    // 300 t * 16 B per (n, nt) tile
#define S1_NSTRIDE 134400  // 28 tiles * 4800 (2 pad tiles: safe reads, zero-weighted)
#define SEGL 19         // fused2 scan segment length (16 segments x 19 >= 300)
#define SEGL2 10        // l2f scan segment length (32 segments x 10 >= 300)

typedef int v4i __attribute__((ext_vector_type(4)));

// ---- k_pack: one thread per (n,t,64k-group); emits 0/1 BYTES (A operand direct) ----
__global__ void k_pack(const float* __restrict__ rand_u, const float* __restrict__ img,
                       uint8_t* __restrict__ s0b) {
  int t = blockIdx.x * 64 + threadIdx.x;
  int w2 = blockIdx.y;                  // 13 groups of 64 k
  int n = blockIdx.z;
  if (t >= TT) return;
  const float* rb = rand_u + (size_t)n * N_I * TT + t;
  const float* ib = img + (size_t)n * N_I;
  uint8_t* dst = s0b + ((size_t)n * TT + t) * NK + w2 * 64;
  int kb = w2 * 64;
  #pragma unroll
  for (int g = 0; g < 4; ++g) {         // 4 x 16B stores = 64 contiguous bytes
    uint32_t wd[4];
    #pragma unroll
    for (int q = 0; q < 4; ++q) {
      uint32_t v = 0;
      #pragma unroll
      for (int b = 0; b < 4; ++b) {
        int i = kb + g * 16 + q * 4 + b;
        float r = (i < N_I) ? rb[(size_t)i * TT] : 2.0f;   // 2.0 > any p -> no spike
        float p = (i < N_I) ? ib[i] : 0.0f;                // uniform -> scalar load
        v |= (r < p ? 1u : 0u) << (8 * b);
      }
      wd[q] = v;
    }
    v4i o; o[0] = (int)wd[0]; o[1] = (int)wd[1]; o[2] = (int)wd[2]; o[3] = (int)wd[3];
    *(v4i*)(dst + g * 16) = o;
  }
}

// ---- k_bprepall: W1 and W2 -> signed-i8 digit matrices, MFMA fragment-major ----
__global__ void k_bprepall(const float* __restrict__ W1, const float* __restrict__ W2,
                           v4i* __restrict__ Bf, v4i* __restrict__ Bf2) {
  int bid  = blockIdx.x;
  int lane = threadIdx.x;
  if (bid < NDIG * NTILES * NKS) {                    // ---- W1 part ----
    int ks   = bid % NKS;
    int rest = bid / NKS;
    int nt   = rest % NTILES;
    int d    = rest / NTILES;
    int o     = nt * 16 + (lane & 15);
    int kbase = ks * 64 + (lane >> 4) * 16;
    uint32_t wds[4] = {0, 0, 0, 0};
    for (int j = 0; j < 16; ++j) {
      int k = kbase + j;
      int dig = 0;
      if (o < N_H && k < N_I) {
        double w = (double)W1[(size_t)o * N_I + k];
        int r = (int)llround(w * 268435456.0);
        for (int dd = 0; dd <= d; ++dd) {
          dig = (int)(int8_t)(uint8_t)(r & 255);
          r = (r - dig) >> 8;
        }
      }
      wds[j >> 2] |= ((uint32_t)(uint8_t)(int8_t)dig) << (8 * (j & 3));
    }
    v4i v; v[0] = (int)wds[0]; v[1] = (int)wds[1]; v[2] = (int)wds[2]; v[3] = (int)wds[3];
    Bf[(size_t)bid * 64 + lane] = v;
  } else {                                            // ---- W2 part ----
    int b2 = bid - NDIG * NTILES * NKS;               // d*NKS2 + ks
    int ks = b2 % NKS2, d = b2 / NKS2;
    int o     = lane & 15;
    int kbase = ks * 64 + (lane >> 4) * 16;
    uint32_t wds[4] = {0, 0, 0, 0};
    for (int j = 0; j < 16; ++j) {
      int k = kbase + j;
      int dig = 0;
      if (o < N_O && k < N_H) {
        double w = (double)W2[(size_t)o * N_H + k];
        int r = (int)llround(w * 268435456.0);
        for (int dd = 0; dd <= d; ++dd) {
          dig = (int)(int8_t)(uint8_t)(r & 255);
          r = (r - dig) >> 8;
        }
      }
      wds[j >> 2] |= ((uint32_t)(uint8_t)(int8_t)dig) << (8 * (j & 3));
    }
    v4i v; v[0] = (int)wds[0]; v[1] = (int)wds[1]; v[2] = (int)wds[2]; v[3] = (int)wds[3];
    Bf2[(size_t)b2 * 64 + lane] = v;
  }
}

// ---- layer-1 MFMA pass over NMT m-tiles (register-split to raise occupancy) ----
template<int NMT>
__device__ __forceinline__ void l1_pass(const uint8_t* __restrict__ an,
                                        const v4i* __restrict__ bb, size_t dstr,
                                        int wave, int lane, int mt0,
                                        double (*tile)[17]) {
  int lrow = lane & 15, quad = lane >> 4;
  v4i acc[NMT][NDIG];
  #pragma unroll
  for (int i = 0; i < NMT; ++i)
    #pragma unroll
    for (int d = 0; d < NDIG; ++d) { acc[i][d][0]=0; acc[i][d][1]=0; acc[i][d][2]=0; acc[i][d][3]=0; }
  const uint8_t* ap[NMT];
  #pragma unroll
  for (int i = 0; i < NMT; ++i) {
    int rr = wave * 80 + (mt0 + i) * 16 + lrow;
    if (rr > TT - 1) rr = TT - 1;                      // clamp; clamped rows unused
    ap[i] = an + (size_t)rr * NK + quad * 16;
  }
  v4i bcur[NDIG], acur[NMT];
  #pragma unroll
  for (int d = 0; d < NDIG; ++d) bcur[d] = bb[d * dstr];
  #pragma unroll
  for (int i = 0; i < NMT; ++i) acur[i] = *(const v4i*)ap[i];
  for (int ks = 0; ks < NKS; ++ks) {
    int ks2 = (ks + 1 < NKS) ? ks + 1 : ks;
    v4i bnxt[NDIG], anxt[NMT];
    #pragma unroll
    for (int d = 0; d < NDIG; ++d) bnxt[d] = bb[d * dstr + ks2 * 64];
    #pragma unroll
    for (int i = 0; i < NMT; ++i) anxt[i] = *(const v4i*)(ap[i] + ks2 * 64);
    #pragma unroll
    for (int i = 0; i < NMT; ++i)
      #pragma unroll
      for (int d = 0; d < NDIG; ++d)
        acc[i][d] = __builtin_amdgcn_mfma_i32_16x16x64_i8(acur[i], bcur[d], acc[i][d], 0, 0, 0);
    #pragma unroll
    for (int d = 0; d < NDIG; ++d) bcur[d] = bnxt[d];
    #pragma unroll
    for (int i = 0; i < NMT; ++i) acur[i] = anxt[i];
  }
  // digit combine (exact integer < 2^53) -> LDS tile (row = t, col = o-in-tile)
  #pragma unroll
  for (int i = 0; i < NMT; ++i)
    #pragma unroll
    for (int r = 0; r < 4; ++r) {
      int m = wave * 80 + (mt0 + i) * 16 + quad * 4 + r;
      if (m < TT) {
        double v = (double)acc[i][0][r]
                 + 256.0      * (double)acc[i][1][r]
                 + 65536.0    * (double)acc[i][2][r]
                 + 16777216.0 * (double)acc[i][3][r];
        tile[m][lrow] = v;
      }
    }
}

// ---- k_fused2: layer-1 i8-digit MFMA + truncated-IIR SRM FIR + threshold -> s1 ----
// Block = 4 waves; grid (26 nt, 128 n). A operand is pre-expanded 0/1 bytes
// (no bit-unpack VALU). MFMA phase runs as two register-light passes (3+2
// m-tiles) so peak regs ~160 -> 3 blocks/CU. One barrier. Scan: all 256
// threads, 16 segments x 16 cols, verified truncated-IIR recurrence.
__global__ __launch_bounds__(256) void k_fused2(const uint8_t* __restrict__ s0b,
                                                const v4i* __restrict__ Bf,
                                                uint8_t* __restrict__ s1) {
  __shared__ double tile[TT][17];                    // 40800 B, padded stride
  int tid = threadIdx.x;
  int wave = tid >> 6, lane = tid & 63;
  int nt = blockIdx.x, n = blockIdx.y;
  const v4i* bb = Bf + (size_t)nt * NKS * 64 + lane;
  const size_t dstr = (size_t)NTILES * NKS * 64;
  const uint8_t* an = s0b + (size_t)n * TT * NK;

  l1_pass<3>(an, bb, dstr, wave, lane, 0, tile);
  l1_pass<2>(an, bb, dstr, wave, lane, 3, tile);
  __syncthreads();

  // ---------- scan phase: all-lane uniform truncated-IIR ----------
  {
    int col = tid & 15;
    int seg = tid >> 4;                 // 16 segments of SEGL=19
    int T0 = seg * SEGL;
    int Wc = T0 - 63; if (Wc < 0) Wc = 0;
    const double q   = exp(-0.1);
    const double q64 = exp(-6.4);
    const double cS  = (exp(1.0) / 10.0) * (1.0 / 268435456.0);
    double s1a = 0.0, s2a = 0.0, s1b = 0.0, s2b = 0.0;
    uint8_t* sb = s1 + (size_t)n * S1_NSTRIDE + (size_t)nt * S1_TILE + col;
    for (int j = 0; j < 63; ++j) {      // warm-up: A-scan only, zero-padded t<0
      int t = T0 - 63 + j;
      int tc = (t < 0) ? 0 : t;
      double xa = (t >= 0) ? tile[tc][col] : 0.0;
      s2a = q * (s2a + s1a);
      s1a = q * s1a + xa;
    }
    for (int j = 0; j < SEGL; ++j) {    // outputs with 64-lagged tail subtraction
      int t = T0 + j;
      int tc = (t > TT - 1) ? TT - 1 : t;
      int tb = t - 64;
      int tbc = (tb < 0) ? 0 : tb;
      double xa = tile[tc][col];
      double xb = (tb >= Wc) ? tile[tbc][col] : 0.0;
      s2b = q * (s2b + s1b);
      s1b = q * s1b + xb;
      s2a = q * (s2a + s1a);
      s1a = q * s1a + xa;
      double y = cS * (s2a - q64 * (s2b + 64.0 * s1b));
      if (t < TT) sb[(size_t)t * 16] = (y >= 10.0) ? 1 : 0;
    }
  }
}

// ---- k_l2f: layer-2 i8-digit MFMA + IIR FIR + threshold -> final spikes ----
// Block = 4 waves, grid (2 half, 128 n): both halves build the (cheap) full
// tile2, then each scans 16 of 32 segments of length 10 -> 256 blocks busy.
__global__ __launch_bounds__(256) void k_l2f(const uint8_t* __restrict__ s1,
                                             const v4i* __restrict__ Bf2,
                                             float* __restrict__ out) {
  __shared__ double tile2[TT][17];                   // stride 17: uniform-lane reads in-bounds
  int tid = threadIdx.x;
  int wave = tid >> 6, lane = tid & 63;
  int half = blockIdx.x, n = blockIdx.y;
  int lrow = lane & 15, quad = lane >> 4;
  const uint8_t* s1n = s1 + (size_t)n * S1_NSTRIDE;
  for (int mt = wave; mt < 19; mt += 4) {
    int m0 = mt * 16;
    int trow = m0 + lrow; if (trow > TT - 1) trow = TT - 1;  // clamp
    v4i acc[NDIG];
    #pragma unroll
    for (int d = 0; d < NDIG; ++d) { acc[d][0]=0; acc[d][1]=0; acc[d][2]=0; acc[d][3]=0; }
    for (int ks = 0; ks < NKS2; ++ks) {
      // A-frag: 16 h-bytes = tile (ks*4+quad), t-row trow (nt-major layout)
      v4i af = *(const v4i*)(s1n + (size_t)(ks * 4 + quad) * S1_TILE + (size_t)trow * 16);
      #pragma unroll
      for (int d = 0; d < NDIG; ++d) {
        v4i bf = Bf2[(size_t)(d * NKS2 + ks) * 64 + lane];
        acc[d] = __builtin_amdgcn_mfma_i32_16x16x64_i8(af, bf, acc[d], 0, 0, 0);
      }
    }
    #pragma unroll
    for (int r = 0; r < 4; ++r) {
      int m = m0 + quad * 4 + r;
      if (m < TT && lrow < N_O) {
        double v = (double)acc[0][r]
                 + 256.0      * (double)acc[1][r]
                 + 65536.0    * (double)acc[2][r]
                 + 16777216.0 * (double)acc[3][r];
        tile2[m][lrow] = v;
      }
    }
  }
  __syncthreads();

  // ---------- scan phase: 16 of 32 segments per block (cols >= N_O masked) ----------
  {
    int col = tid & 15;
    int seg = half * 16 + (tid >> 4);
    int T0 = seg * SEGL2;
    int Wc = T0 - 63; if (Wc < 0) Wc = 0;
    const double q   = exp(-0.1);
    const double q64 = exp(-6.4);
    const double cS  = (exp(1.0) / 10.0) * (1.0 / 268435456.0);
    double s1a = 0.0, s2a = 0.0, s1b = 0.0, s2b = 0.0;
    float* ob = out + (size_t)n * N_O * TT + (size_t)col * TT;
    for (int j = 0; j < 63; ++j) {
      int t = T0 - 63 + j;
      int tc = (t < 0) ? 0 : t;
      tc = (tc > TT - 1) ? TT - 1 : tc;
      double xa = (t >= 0 && t < TT + 63) ? tile2[tc][col] : 0.0;
      if (t >= TT) xa = 0.0;            // segments past the end: inert
      s2a = q * (s2a + s1a);
      s1a = q * s1a + xa;
    }
    for (int j = 0; j < SEGL2; ++j) {
      int t = T0 + j;
      int tc = (t > TT - 1) ? TT - 1 : t;
      int tb = t - 64;
      int tbc = (tb < 0) ? 0 : tb;
      tbc = (tbc > TT - 1) ? TT - 1 : tbc;
      double xa = tile2[tc][col];
      double xb = (tb >= Wc) ? tile2[tbc][col] : 0.0;
      s2b = q * (s2b + s1b);
      s1b = q * s1b + xb;
      s2a = q * (s2a + s1a);
      s1a = q * s1a + xa;
      double y = cS * (s2a - q64 * (s2b + 64.0 * s1b));
      if (t < TT && col < N_O) ob[t] = (y >= 10.0) ? 1.0f : 0.0f;
    }
  }
}

extern "C" void kernel_launch(void* const* d_in, const int* in_sizes, int n_in,
                              void* d_out, int out_size, void* d_ws, size_t ws_size,
                              hipStream_t stream) {
  const float* img   = (const float*)d_in[0];
  const float* randu = (const float*)d_in[1];
  const float* W1    = (const float*)d_in[2];
  const float* W2    = (const float*)d_in[3];
  float* out = (float*)d_out;

  char* ws = (char*)d_ws;
  size_t off = 0;
  auto alloc = [&](size_t bytes) -> void* {
    void* p = ws + off;
    off = (off + bytes + 511) & ~(size_t)511;
    return p;
  };
  uint8_t*  s0b = (uint8_t*) alloc((size_t)N_B * TT * NK);                      // 31.9 MB
  v4i*      Bf  = (v4i*)     alloc((size_t)NDIG * NTILES * NKS * 64 * 16);      // 1.4 MB
  v4i*      Bf2 = (v4i*)     alloc((size_t)NDIG * NKS2 * 64 * 16);              // 28 KB
  uint8_t*  s1  = (uint8_t*) alloc((size_t)N_B * S1_NSTRIDE);                   // 17.2 MB
  if (off > ws_size) return;

  k_pack    <<<dim3(5, NKS, N_B), 64, 0, stream>>>(randu, img, s0b);
  k_bprepall<<<dim3(NDIG * NTILES * NKS + NDIG * NKS2), 64, 0, stream>>>(W1, W2, Bf, Bf2);
  k_fused2  <<<dim3(NTILES, N_B), 256, 0, stream>>>(s0b, Bf, s1);
  k_l2f     <<<dim3(2, N_B), 256, 0, stream>>>(s1, Bf2, out);
}

// Round 3
// 345.914 us; speedup vs baseline: 1.2250x; 1.2250x over previous
//
#include <hip/hip_runtime.h>
#include <cstdint>
#include <cstddef>

#define N_B 128
#define N_I 784
#define N_H 410
#define N_O 10
#define TT  300
#define KL  64
#define NK  832         // K-padded input features (13 * 64)
#define NKS 13          // layer-1 K-steps of 64 (832)
#define NTILES 26       // layer-1 N-tiles of 16 (410 -> 416)
#define NDIG 4          // base-256 digits of round(W * 2^28)
#define NKS2 7          // layer-2 K-steps of 64 (448)
#define S1_TILE 4800    // 300 t * 16 B per (n, nt) tile
#define S1_NSTRIDE 134400  // 28 tiles * 4800 (2 pad tiles: safe reads, zero-weighted)
#define SEGL 19         // fused2 scan segment length (16 segments x 19 >= 300)
#define NWG1 (NTILES * N_B)   // 3328 fused2 workgroups (3328 % 8 == 0)
#define WPX  (NWG1 / 8)       // 416 = 16 * 26: each XCD owns exactly 16 n's

typedef int v4i __attribute__((ext_vector_type(4)));

// ---- k_pack: one thread per (n,t,64k-group); emits 0/1 BYTES (A operand direct) ----
// (verified correct in R2)
__global__ void k_pack(const float* __restrict__ rand_u, const float* __restrict__ img,
                       uint8_t* __restrict__ s0b) {
  int t = blockIdx.x * 64 + threadIdx.x;
  int w2 = blockIdx.y;                  // 13 groups of 64 k
  int n = blockIdx.z;
  if (t >= TT) return;
  const float* rb = rand_u + (size_t)n * N_I * TT + t;
  const float* ib = img + (size_t)n * N_I;
  uint8_t* dst = s0b + ((size_t)n * TT + t) * NK + w2 * 64;
  int kb = w2 * 64;
  #pragma unroll
  for (int g = 0; g < 4; ++g) {         // 4 x 16B stores = 64 contiguous bytes
    uint32_t wd[4];
    #pragma unroll
    for (int q = 0; q < 4; ++q) {
      uint32_t v = 0;
      #pragma unroll
      for (int b = 0; b < 4; ++b) {
        int i = kb + g * 16 + q * 4 + b;
        float r = (i < N_I) ? rb[(size_t)i * TT] : 2.0f;   // 2.0 > any p -> no spike
        float p = (i < N_I) ? ib[i] : 0.0f;                // uniform -> scalar load
        v |= (r < p ? 1u : 0u) << (8 * b);
      }
      wd[q] = v;
    }
    v4i o; o[0] = (int)wd[0]; o[1] = (int)wd[1]; o[2] = (int)wd[2]; o[3] = (int)wd[3];
    *(v4i*)(dst + g * 16) = o;
  }
}

// ---- k_bprepall: W1 and W2 -> signed-i8 digit matrices, MFMA fragment-major ----
__global__ void k_bprepall(const float* __restrict__ W1, const float* __restrict__ W2,
                           v4i* __restrict__ Bf, v4i* __restrict__ Bf2) {
  int bid  = blockIdx.x;
  int lane = threadIdx.x;
  if (bid < NDIG * NTILES * NKS) {                    // ---- W1 part ----
    int ks   = bid % NKS;
    int rest = bid / NKS;
    int nt   = rest % NTILES;
    int d    = rest / NTILES;
    int o     = nt * 16 + (lane & 15);
    int kbase = ks * 64 + (lane >> 4) * 16;
    uint32_t wds[4] = {0, 0, 0, 0};
    for (int j = 0; j < 16; ++j) {
      int k = kbase + j;
      int dig = 0;
      if (o < N_H && k < N_I) {
        double w = (double)W1[(size_t)o * N_I + k];
        int r = (int)llround(w * 268435456.0);
        for (int dd = 0; dd <= d; ++dd) {
          dig = (int)(int8_t)(uint8_t)(r & 255);
          r = (r - dig) >> 8;
        }
      }
      wds[j >> 2] |= ((uint32_t)(uint8_t)(int8_t)dig) << (8 * (j & 3));
    }
    v4i v; v[0] = (int)wds[0]; v[1] = (int)wds[1]; v[2] = (int)wds[2]; v[3] = (int)wds[3];
    Bf[(size_t)bid * 64 + lane] = v;
  } else {                                            // ---- W2 part ----
    int b2 = bid - NDIG * NTILES * NKS;               // d*NKS2 + ks
    int ks = b2 % NKS2, d = b2 / NKS2;
    int o     = lane & 15;
    int kbase = ks * 64 + (lane >> 4) * 16;
    uint32_t wds[4] = {0, 0, 0, 0};
    for (int j = 0; j < 16; ++j) {
      int k = kbase + j;
      int dig = 0;
      if (o < N_O && k < N_H) {
        double w = (double)W2[(size_t)o * N_H + k];
        int r = (int)llround(w * 268435456.0);
        for (int dd = 0; dd <= d; ++dd) {
          dig = (int)(int8_t)(uint8_t)(r & 255);
          r = (r - dig) >> 8;
        }
      }
      wds[j >> 2] |= ((uint32_t)(uint8_t)(int8_t)dig) << (8 * (j & 3));
    }
    v4i v; v[0] = (int)wds[0]; v[1] = (int)wds[1]; v[2] = (int)wds[2]; v[3] = (int)wds[3];
    Bf2[(size_t)b2 * 64 + lane] = v;
  }
}

// ---- k_fused2: layer-1 i8-digit MFMA + truncated-IIR SRM FIR + threshold -> s1 ----
// Flat grid 3328, XCD-bijective swizzle: xcd = bid%8 owns n in [16*xcd, 16*xcd+16)
// exclusively (416 = 16*26), so the per-n byte-A slice (250 KB) stays resident in
// that XCD's L2 across its 26 nt-blocks. A operand = pre-expanded 0/1 bytes
// (direct v4i loads, no unpack VALU -- R2 verified). Single-pass acc[5][4]
// register structure (R1 verified). Scan: R1-verified all-lane truncated IIR.
__global__ __launch_bounds__(256) void k_fused2(const uint8_t* __restrict__ s0b,
                                                const v4i* __restrict__ Bf,
                                                uint8_t* __restrict__ s1) {
  __shared__ double tile[TT][17];                    // 40800 B, padded stride
  int tid = threadIdx.x;
  int wave = tid >> 6, lane = tid & 63;
  int bid = blockIdx.x;
  int sw = (bid & 7) * WPX + (bid >> 3);             // XCD-bijective swizzle
  int n = sw / NTILES, nt = sw % NTILES;
  int lrow = lane & 15, quad = lane >> 4;
  const v4i* bb = Bf + (size_t)nt * NKS * 64 + lane;
  const size_t dstr = (size_t)NTILES * NKS * 64;
  const uint8_t* an = s0b + (size_t)n * TT * NK + quad * 16;

  // ---------- MFMA phase ----------
  v4i acc[5][NDIG];
  #pragma unroll
  for (int mti = 0; mti < 5; ++mti)
    #pragma unroll
    for (int d = 0; d < NDIG; ++d) { acc[mti][d][0]=0; acc[mti][d][1]=0; acc[mti][d][2]=0; acc[mti][d][3]=0; }
  const uint8_t* ap[5];
  #pragma unroll
  for (int mti = 0; mti < 5; ++mti) {
    int rr = wave * 80 + mti * 16 + lrow;
    if (rr > TT - 1) rr = TT - 1;                    // clamp; clamped rows unused
    ap[mti] = an + (size_t)rr * NK;
  }
  v4i bcur[NDIG], acur[5];
  #pragma unroll
  for (int d = 0; d < NDIG; ++d) bcur[d] = bb[d * dstr];
  #pragma unroll
  for (int mti = 0; mti < 5; ++mti) acur[mti] = *(const v4i*)ap[mti];
  for (int ks = 0; ks < NKS; ++ks) {
    int ks2 = (ks + 1 < NKS) ? ks + 1 : ks;
    v4i bnxt[NDIG], anxt[5];
    #pragma unroll
    for (int d = 0; d < NDIG; ++d) bnxt[d] = bb[d * dstr + ks2 * 64];
    #pragma unroll
    for (int mti = 0; mti < 5; ++mti) anxt[mti] = *(const v4i*)(ap[mti] + ks2 * 64);
    #pragma unroll
    for (int mti = 0; mti < 5; ++mti)
      #pragma unroll
      for (int d = 0; d < NDIG; ++d)
        acc[mti][d] = __builtin_amdgcn_mfma_i32_16x16x64_i8(acur[mti], bcur[d], acc[mti][d], 0, 0, 0);
    #pragma unroll
    for (int d = 0; d < NDIG; ++d) bcur[d] = bnxt[d];
    #pragma unroll
    for (int mti = 0; mti < 5; ++mti) acur[mti] = anxt[mti];
  }
  // digit combine (exact integer < 2^53) -> LDS tile (row = t, col = o-in-tile)
  #pragma unroll
  for (int mti = 0; mti < 5; ++mti)
    #pragma unroll
    for (int r = 0; r < 4; ++r) {
      int m = wave * 80 + mti * 16 + quad * 4 + r;
      if (m < TT) {
        double v = (double)acc[mti][0][r]
                 + 256.0      * (double)acc[mti][1][r]
                 + 65536.0    * (double)acc[mti][2][r]
                 + 16777216.0 * (double)acc[mti][3][r];
        tile[m][lrow] = v;
      }
    }
  __syncthreads();

  // ---------- scan phase: all-lane uniform truncated-IIR (R1 verified) ----------
  {
    int col = tid & 15;
    int seg = tid >> 4;                 // 16 segments of SEGL=19
    int T0 = seg * SEGL;
    int Wc = T0 - 63; if (Wc < 0) Wc = 0;
    const double q   = exp(-0.1);
    const double q64 = exp(-6.4);
    const double cS  = (exp(1.0) / 10.0) * (1.0 / 268435456.0);
    double s1a = 0.0, s2a = 0.0, s1b = 0.0, s2b = 0.0;
    uint8_t* sb = s1 + (size_t)n * S1_NSTRIDE + (size_t)nt * S1_TILE + col;
    for (int j = 0; j < 63; ++j) {      // warm-up: A-scan only, zero-padded t<0
      int t = T0 - 63 + j;
      int tc = (t < 0) ? 0 : t;
      double xa = (t >= 0) ? tile[tc][col] : 0.0;
      s2a = q * (s2a + s1a);
      s1a = q * s1a + xa;
    }
    for (int j = 0; j < SEGL; ++j) {    // outputs with 64-lagged tail subtraction
      int t = T0 + j;
      int tc = (t > TT - 1) ? TT - 1 : t;
      int tb = t - 64;
      int tbc = (tb < 0) ? 0 : tb;
      double xa = tile[tc][col];
      double xb = (tb >= Wc) ? tile[tbc][col] : 0.0;
      s2b = q * (s2b + s1b);
      s1b = q * s1b + xb;
      s2a = q * (s2a + s1a);
      s1a = q * s1a + xa;
      double y = cS * (s2a - q64 * (s2b + 64.0 * s1b));
      if (t < TT) sb[(size_t)t * 16] = (y >= 10.0) ? 1 : 0;
    }
  }
}

// ---- k_l2f: layer-2 i8-digit MFMA + IIR FIR + threshold -> final spikes ----
// Block = 4 waves, grid (128 n). 19 m-tiles over waves -> LDS -> all-lane scan.
// (R1 verified)
__global__ __launch_bounds__(256) void k_l2f(const uint8_t* __restrict__ s1,
                                             const v4i* __restrict__ Bf2,
                                             float* __restrict__ out) {
  __shared__ double tile2[TT][17];                   // stride 17: uniform-lane reads in-bounds
  int tid = threadIdx.x;
  int wave = tid >> 6, lane = tid & 63;
  int n = blockIdx.x;
  int lrow = lane & 15, quad = lane >> 4;
  const uint8_t* s1n = s1 + (size_t)n * S1_NSTRIDE;
  for (int mt = wave; mt < 19; mt += 4) {
    int m0 = mt * 16;
    int trow = m0 + lrow; if (trow > TT - 1) trow = TT - 1;  // clamp
    v4i acc[NDIG];
    #pragma unroll
    for (int d = 0; d < NDIG; ++d) { acc[d][0]=0; acc[d][1]=0; acc[d][2]=0; acc[d][3]=0; }
    for (int ks = 0; ks < NKS2; ++ks) {
      // A-frag: 16 h-bytes = tile (ks*4+quad), t-row trow (nt-major layout)
      v4i af = *(const v4i*)(s1n + (size_t)(ks * 4 + quad) * S1_TILE + (size_t)trow * 16);
      #pragma unroll
      for (int d = 0; d < NDIG; ++d) {
        v4i bf = Bf2[(size_t)(d * NKS2 + ks) * 64 + lane];
        acc[d] = __builtin_amdgcn_mfma_i32_16x16x64_i8(af, bf, acc[d], 0, 0, 0);
      }
    }
    #pragma unroll
    for (int r = 0; r < 4; ++r) {
      int m = m0 + quad * 4 + r;
      if (m < TT && lrow < N_O) {
        double v = (double)acc[0][r]
                 + 256.0      * (double)acc[1][r]
                 + 65536.0    * (double)acc[2][r]
                 + 16777216.0 * (double)acc[3][r];
        tile2[m][lrow] = v;
      }
    }
  }
  __syncthreads();

  // ---------- scan phase: all-lane uniform (cols >= N_O masked at store) ----------
  {
    int col = tid & 15;
    int seg = tid >> 4;
    int T0 = seg * SEGL;
    int Wc = T0 - 63; if (Wc < 0) Wc = 0;
    const double q   = exp(-0.1);
    const double q64 = exp(-6.4);
    const double cS  = (exp(1.0) / 10.0) * (1.0 / 268435456.0);
    double s1a = 0.0, s2a = 0.0, s1b = 0.0, s2b = 0.0;
    float* ob = out + (size_t)n * N_O * TT + (size_t)col * TT;
    for (int j = 0; j < 63; ++j) {
      int t = T0 - 63 + j;
      int tc = (t < 0) ? 0 : t;
      double xa = (t >= 0) ? tile2[tc][col] : 0.0;
      s2a = q * (s2a + s1a);
      s1a = q * s1a + xa;
    }
    for (int j = 0; j < SEGL; ++j) {
      int t = T0 + j;
      int tc = (t > TT - 1) ? TT - 1 : t;
      int tb = t - 64;
      int tbc = (tb < 0) ? 0 : tb;
      double xa = tile2[tc][col];
      double xb = (tb >= Wc) ? tile2[tbc][col] : 0.0;
      s2b = q * (s2b + s1b);
      s1b = q * s1b + xb;
      s2a = q * (s2a + s1a);
      s1a = q * s1a + xa;
      double y = cS * (s2a - q64 * (s2b + 64.0 * s1b));
      if (t < TT && col < N_O) ob[t] = (y >= 10.0) ? 1.0f : 0.0f;
    }
  }
}

extern "C" void kernel_launch(void* const* d_in, const int* in_sizes, int n_in,
                              void* d_out, int out_size, void* d_ws, size_t ws_size,
                              hipStream_t stream) {
  const float* img   = (const float*)d_in[0];
  const float* randu = (const float*)d_in[1];
  const float* W1    = (const float*)d_in[2];
  const float* W2    = (const float*)d_in[3];
  float* out = (float*)d_out;

  char* ws = (char*)d_ws;
  size_t off = 0;
  auto alloc = [&](size_t bytes) -> void* {
    void* p = ws + off;
    off = (off + bytes + 511) & ~(size_t)511;
    return p;
  };
  uint8_t*  s0b = (uint8_t*) alloc((size_t)N_B * TT * NK);                      // 31.9 MB
  v4i*      Bf  = (v4i*)     alloc((size_t)NDIG * NTILES * NKS * 64 * 16);      // 1.4 MB
  v4i*      Bf2 = (v4i*)     alloc((size_t)NDIG * NKS2 * 64 * 16);              // 28 KB
  uint8_t*  s1  = (uint8_t*) alloc((size_t)N_B * S1_NSTRIDE);                   // 17.2 MB
  if (off > ws_size) return;

  k_pack    <<<dim3(5, NKS, N_B), 64, 0, stream>>>(randu, img, s0b);
  k_bprepall<<<dim3(NDIG * NTILES * NKS + NDIG * NKS2), 64, 0, stream>>>(W1, W2, Bf, Bf2);
  k_fused2  <<<dim3(NWG1), 256, 0, stream>>>(s0b, Bf, s1);
  k_l2f     <<<dim3(N_B), 256, 0, stream>>>(s1, Bf2, out);
}

// Round 4
// 311.629 us; speedup vs baseline: 1.3597x; 1.1100x over previous
//
#include <hip/hip_runtime.h>
#include <cstdint>
#include <cstddef>

#define N_B 128
#define N_I 784
#define N_H 410
#define N_O 10
#define TT  300
#define KL  64
#define NK  832         // K-padded input features (13 * 64)
#define NKS 13          // layer-1 K-steps of 64 (832)
#define NTILES 26       // layer-1 N-tiles of 16 (410 -> 416)
#define NDIG 4          // base-256 digits of round(W * 2^28)
#define NKS2 7          // layer-2 K-steps of 64 (448)
#define S1_TILE 4800    // 300 t * 16 B per (n, nt) tile
#define S1_NSTRIDE 134400  // 28 tiles * 4800 (2 pad tiles: safe reads, zero-weighted)
#define SEGL 19         // fused2 scan segment length (16 segments x 19 >= 300)
#define SEGL2 10        // l2f scan segment length (32 segments x 10 >= 300)
#define NWG1 (NTILES * N_B)   // 3328 fused2 workgroups (3328 % 8 == 0)
#define WPX  (NWG1 / 8)       // 416 = 16 * 26: each XCD owns exactly 16 n's
#define DBYTES (NTILES * NKS * 1024)   // byte stride between W1 digit planes in Bf

typedef int v4i __attribute__((ext_vector_type(4)));

// async global->LDS, 16 B per lane; LDS dst is wave-uniform base (+ lane*16 by HW)
__device__ __forceinline__ void glds16(const void* g, void* l) {
  __builtin_amdgcn_global_load_lds(
      (const __attribute__((address_space(1))) uint32_t*)g,
      (__attribute__((address_space(3))) uint32_t*)l, 16, 0, 0);
}

// ---- k_pack: one thread per (n,t,64k-group); emits 0/1 BYTES (A operand direct) ----
// (verified correct in R2/R3)
__global__ void k_pack(const float* __restrict__ rand_u, const float* __restrict__ img,
                       uint8_t* __restrict__ s0b) {
  int t = blockIdx.x * 64 + threadIdx.x;
  int w2 = blockIdx.y;                  // 13 groups of 64 k
  int n = blockIdx.z;
  if (t >= TT) return;
  const float* rb = rand_u + (size_t)n * N_I * TT + t;
  const float* ib = img + (size_t)n * N_I;
  uint8_t* dst = s0b + ((size_t)n * TT + t) * NK + w2 * 64;
  int kb = w2 * 64;
  #pragma unroll
  for (int g = 0; g < 4; ++g) {         // 4 x 16B stores = 64 contiguous bytes
    uint32_t wd[4];
    #pragma unroll
    for (int q = 0; q < 4; ++q) {
      uint32_t v = 0;
      #pragma unroll
      for (int b = 0; b < 4; ++b) {
        int i = kb + g * 16 + q * 4 + b;
        float r = (i < N_I) ? rb[(size_t)i * TT] : 2.0f;   // 2.0 > any p -> no spike
        float p = (i < N_I) ? ib[i] : 0.0f;                // uniform -> scalar load
        v |= (r < p ? 1u : 0u) << (8 * b);
      }
      wd[q] = v;
    }
    v4i o; o[0] = (int)wd[0]; o[1] = (int)wd[1]; o[2] = (int)wd[2]; o[3] = (int)wd[3];
    *(v4i*)(dst + g * 16) = o;
  }
}

// ---- k_bprepall: W1 and W2 -> signed-i8 digit matrices, MFMA fragment-major ----
__global__ void k_bprepall(const float* __restrict__ W1, const float* __restrict__ W2,
                           v4i* __restrict__ Bf, v4i* __restrict__ Bf2) {
  int bid  = blockIdx.x;
  int lane = threadIdx.x;
  if (bid < NDIG * NTILES * NKS) {                    // ---- W1 part ----
    int ks   = bid % NKS;
    int rest = bid / NKS;
    int nt   = rest % NTILES;
    int d    = rest / NTILES;
    int o     = nt * 16 + (lane & 15);
    int kbase = ks * 64 + (lane >> 4) * 16;
    uint32_t wds[4] = {0, 0, 0, 0};
    for (int j = 0; j < 16; ++j) {
      int k = kbase + j;
      int dig = 0;
      if (o < N_H && k < N_I) {
        double w = (double)W1[(size_t)o * N_I + k];
        int r = (int)llround(w * 268435456.0);
        for (int dd = 0; dd <= d; ++dd) {
          dig = (int)(int8_t)(uint8_t)(r & 255);
          r = (r - dig) >> 8;
        }
      }
      wds[j >> 2] |= ((uint32_t)(uint8_t)(int8_t)dig) << (8 * (j & 3));
    }
    v4i v; v[0] = (int)wds[0]; v[1] = (int)wds[1]; v[2] = (int)wds[2]; v[3] = (int)wds[3];
    Bf[(size_t)bid * 64 + lane] = v;
  } else {                                            // ---- W2 part ----
    int b2 = bid - NDIG * NTILES * NKS;               // d*NKS2 + ks
    int ks = b2 % NKS2, d = b2 / NKS2;
    int o     = lane & 15;
    int kbase = ks * 64 + (lane >> 4) * 16;
    uint32_t wds[4] = {0, 0, 0, 0};
    for (int j = 0; j < 16; ++j) {
      int k = kbase + j;
      int dig = 0;
      if (o < N_O && k < N_H) {
        double w = (double)W2[(size_t)o * N_H + k];
        int r = (int)llround(w * 268435456.0);
        for (int dd = 0; dd <= d; ++dd) {
          dig = (int)(int8_t)(uint8_t)(r & 255);
          r = (r - dig) >> 8;
        }
      }
      wds[j >> 2] |= ((uint32_t)(uint8_t)(int8_t)dig) << (8 * (j & 3));
    }
    v4i v; v[0] = (int)wds[0]; v[1] = (int)wds[1]; v[2] = (int)wds[2]; v[3] = (int)wds[3];
    Bf2[(size_t)b2 * 64 + lane] = v;
  }
}

// ---- k_fused2: layer-1 i8-digit MFMA + truncated-IIR SRM FIR + threshold -> s1 ----
// 2-iteration-deep glds pipeline, wave-private staging (no K-loop barriers):
//   per iter: vmcnt(9) retires the 2-iter-old batch (one batch of 9 stays in
//   flight); ds_read next-iter fragments to regs; MFMA current; lgkmcnt(0)
//   fence; issue glds batch(ks+3) into the parity just consumed.
// LDS: A-stage 2x4x5120 + B-stage 2x4x4096 = 73728 B; tile[300][17] (40800 B)
// ALIASES the staging region (staging dead after the K-loop; barrier between).
__global__ __launch_bounds__(256) void k_fused2(const uint8_t* __restrict__ s0b,
                                                const v4i* __restrict__ Bf,
                                                uint8_t* __restrict__ s1) {
  __shared__ __align__(16) uint8_t smem[73728];
  uint8_t* bufA = smem;                       // [2][4 waves][5120]
  uint8_t* bufB = smem + 40960;               // [2][4 waves][4096]
  double (*tile)[17] = (double (*)[17])smem;  // alias, valid after barrier1

  int tid = threadIdx.x;
  int wave = tid >> 6, lane = tid & 63;
  int bid = blockIdx.x;
  int sw = (bid & 7) * WPX + (bid >> 3);      // XCD-bijective swizzle (R3 verified)
  int n = sw / NTILES, nt = sw % NTILES;
  int lrow = lane & 15, quad = lane >> 4;

  const uint8_t* an0 = s0b + (size_t)n * TT * NK;
  int arow = wave * 80 + (lane >> 2);         // + c*16 per chunk
  int acol = (lane & 3) * 16;
  const uint8_t* bfb = (const uint8_t*)Bf + (size_t)nt * NKS * 1024 + (size_t)lane * 16;

  auto STAGE = [&](int k, int par) {          // 9 glds, uniform across waves/lanes
    uint8_t* ad = bufA + par * 20480 + wave * 5120;
    #pragma unroll
    for (int c = 0; c < 5; ++c) {
      int r = arow + c * 16; if (r > TT - 1) r = TT - 1;   // clamp: rows>=300 load dup data, outputs discarded
      glds16(an0 + (size_t)r * NK + (size_t)k * 64 + acol, ad + c * 1024);
    }
    uint8_t* bd = bufB + par * 16384 + wave * 4096;
    #pragma unroll
    for (int d = 0; d < NDIG; ++d)
      glds16(bfb + (size_t)d * DBYTES + (size_t)k * 1024, bd + d * 1024);
  };
  auto LDA = [&](int par, v4i* a) {
    const uint8_t* base = bufA + par * 20480 + wave * 5120 + quad * 16;
    #pragma unroll
    for (int m = 0; m < 5; ++m)
      a[m] = *(const v4i*)(base + (size_t)(m * 16 + lrow) * 64);
  };
  auto LDB = [&](int par, v4i* b) {
    const uint8_t* base = bufB + par * 16384 + wave * 4096 + lane * 16;
    #pragma unroll
    for (int d = 0; d < NDIG; ++d)
      b[d] = *(const v4i*)(base + (size_t)d * 1024);
  };

  // ---------- MFMA phase ----------
  v4i acc[5][NDIG];
  #pragma unroll
  for (int m = 0; m < 5; ++m)
    #pragma unroll
    for (int d = 0; d < NDIG; ++d) { acc[m][d][0]=0; acc[m][d][1]=0; acc[m][d][2]=0; acc[m][d][3]=0; }

  STAGE(0, 0);
  STAGE(1, 1);
  asm volatile("s_waitcnt vmcnt(9)" ::: "memory");   // batch0 landed; batch1 in flight
  v4i acur[5], bcur[NDIG], anxt[5], bnxt[NDIG];
  LDA(0, acur); LDB(0, bcur);
  asm volatile("s_waitcnt lgkmcnt(0)" ::: "memory"); // frags in regs before overwrite
  __builtin_amdgcn_sched_barrier(0);
  STAGE(2, 0);

  #pragma unroll
  for (int ks = 0; ks < NKS; ++ks) {
    if (ks < NKS - 2) { asm volatile("s_waitcnt vmcnt(9)" ::: "memory"); }  // retire batch(ks+1)
    else              { asm volatile("s_waitcnt vmcnt(0)" ::: "memory"); }  // tail: nothing else in flight
    int pn = (ks + 1) & 1;
    if (ks < NKS - 1) { LDA(pn, anxt); LDB(pn, bnxt); }
    #pragma unroll
    for (int m = 0; m < 5; ++m)
      #pragma unroll
      for (int d = 0; d < NDIG; ++d)
        acc[m][d] = __builtin_amdgcn_mfma_i32_16x16x64_i8(acur[m], bcur[d], acc[m][d], 0, 0, 0);
    asm volatile("s_waitcnt lgkmcnt(0)" ::: "memory"); // next-frag reads done before parity overwrite
    __builtin_amdgcn_sched_barrier(0);
    if (ks < NKS - 3) STAGE(ks + 3, (ks + 3) & 1);
    if (ks < NKS - 1) {
      #pragma unroll
      for (int m = 0; m < 5; ++m) acur[m] = anxt[m];
      #pragma unroll
      for (int d = 0; d < NDIG; ++d) bcur[d] = bnxt[d];
    }
  }

  __syncthreads();   // barrier1: staging dead everywhere; tile may now alias it

  // digit combine (exact integer < 2^53) -> LDS tile (row = t, col = o-in-tile)
  #pragma unroll
  for (int m5 = 0; m5 < 5; ++m5)
    #pragma unroll
    for (int r = 0; r < 4; ++r) {
      int m = wave * 80 + m5 * 16 + quad * 4 + r;
      if (m < TT) {
        double v = (double)acc[m5][0][r]
                 + 256.0      * (double)acc[m5][1][r]
                 + 65536.0    * (double)acc[m5][2][r]
                 + 16777216.0 * (double)acc[m5][3][r];
        tile[m][lrow] = v;
      }
    }
  __syncthreads();   // barrier2

  // ---------- scan phase: all-lane uniform truncated-IIR (R1 verified) ----------
  {
    int col = tid & 15;
    int seg = tid >> 4;                 // 16 segments of SEGL=19
    int T0 = seg * SEGL;
    int Wc = T0 - 63; if (Wc < 0) Wc = 0;
    const double q   = exp(-0.1);
    const double q64 = exp(-6.4);
    const double cS  = (exp(1.0) / 10.0) * (1.0 / 268435456.0);
    double s1a = 0.0, s2a = 0.0, s1b = 0.0, s2b = 0.0;
    uint8_t* sb = s1 + (size_t)n * S1_NSTRIDE + (size_t)nt * S1_TILE + col;
    for (int j = 0; j < 63; ++j) {      // warm-up: A-scan only, zero-padded t<0
      int t = T0 - 63 + j;
      int tc = (t < 0) ? 0 : t;
      double xa = (t >= 0) ? tile[tc][col] : 0.0;
      s2a = q * (s2a + s1a);
      s1a = q * s1a + xa;
    }
    for (int j = 0; j < SEGL; ++j) {    // outputs with 64-lagged tail subtraction
      int t = T0 + j;
      int tc = (t > TT - 1) ? TT - 1 : t;
      int tb = t - 64;
      int tbc = (tb < 0) ? 0 : tb;
      double xa = tile[tc][col];
      double xb = (tb >= Wc) ? tile[tbc][col] : 0.0;
      s2b = q * (s2b + s1b);
      s1b = q * s1b + xb;
      s2a = q * (s2a + s1a);
      s1a = q * s1a + xa;
      double y = cS * (s2a - q64 * (s2b + 64.0 * s1b));
      if (t < TT) sb[(size_t)t * 16] = (y >= 10.0) ? 1 : 0;
    }
  }
}

// ---- k_l2f: layer-2 i8-digit MFMA + IIR FIR + threshold -> final spikes ----
// Block = 4 waves, grid (2 half, 128 n): both halves build the (cheap) full
// tile2, then each scans 16 of 32 segments of length 10. (R2 verified)
__global__ __launch_bounds__(256) void k_l2f(const uint8_t* __restrict__ s1,
                                             const v4i* __restrict__ Bf2,
                                             float* __restrict__ out) {
  __shared__ double tile2[TT][17];                   // stride 17: uniform-lane reads in-bounds
  int tid = threadIdx.x;
  int wave = tid >> 6, lane = tid & 63;
  int half = blockIdx.x, n = blockIdx.y;
  int lrow = lane & 15, quad = lane >> 4;
  const uint8_t* s1n = s1 + (size_t)n * S1_NSTRIDE;
  for (int mt = wave; mt < 19; mt += 4) {
    int m0 = mt * 16;
    int trow = m0 + lrow; if (trow > TT - 1) trow = TT - 1;  // clamp
    v4i acc[NDIG];
    #pragma unroll
    for (int d = 0; d < NDIG; ++d) { acc[d][0]=0; acc[d][1]=0; acc[d][2]=0; acc[d][3]=0; }
    for (int ks = 0; ks < NKS2; ++ks) {
      // A-frag: 16 h-bytes = tile (ks*4+quad), t-row trow (nt-major layout)
      v4i af = *(const v4i*)(s1n + (size_t)(ks * 4 + quad) * S1_TILE + (size_t)trow * 16);
      #pragma unroll
      for (int d = 0; d < NDIG; ++d) {
        v4i bf = Bf2[(size_t)(d * NKS2 + ks) * 64 + lane];
        acc[d] = __builtin_amdgcn_mfma_i32_16x16x64_i8(af, bf, acc[d], 0, 0, 0);
      }
    }
    #pragma unroll
    for (int r = 0; r < 4; ++r) {
      int m = m0 + quad * 4 + r;
      if (m < TT && lrow < N_O) {
        double v = (double)acc[0][r]
                 + 256.0      * (double)acc[1][r]
                 + 65536.0    * (double)acc[2][r]
                 + 16777216.0 * (double)acc[3][r];
        tile2[m][lrow] = v;
      }
    }
  }
  __syncthreads();

  // ---------- scan phase: 16 of 32 segments per block (cols >= N_O masked) ----------
  {
    int col = tid & 15;
    int seg = half * 16 + (tid >> 4);
    int T0 = seg * SEGL2;
    int Wc = T0 - 63; if (Wc < 0) Wc = 0;
    const double q   = exp(-0.1);
    const double q64 = exp(-6.4);
    const double cS  = (exp(1.0) / 10.0) * (1.0 / 268435456.0);
    double s1a = 0.0, s2a = 0.0, s1b = 0.0, s2b = 0.0;
    float* ob = out + (size_t)n * N_O * TT + (size_t)col * TT;
    for (int j = 0; j < 63; ++j) {
      int t = T0 - 63 + j;
      int tc = (t < 0) ? 0 : t;
      tc = (tc > TT - 1) ? TT - 1 : tc;
      double xa = (t >= 0 && t < TT) ? tile2[tc][col] : 0.0;
      s2a = q * (s2a + s1a);
      s1a = q * s1a + xa;
    }
    for (int j = 0; j < SEGL2; ++j) {
      int t = T0 + j;
      int tc = (t > TT - 1) ? TT - 1 : t;
      int tb = t - 64;
      int tbc = (tb < 0) ? 0 : tb;
      tbc = (tbc > TT - 1) ? TT - 1 : tbc;
      double xa = tile2[tc][col];
      double xb = (tb >= Wc) ? tile2[tbc][col] : 0.0;
      s2b = q * (s2b + s1b);
      s1b = q * s1b + xb;
      s2a = q * (s2a + s1a);
      s1a = q * s1a + xa;
      double y = cS * (s2a - q64 * (s2b + 64.0 * s1b));
      if (t < TT && col < N_O) ob[t] = (y >= 10.0) ? 1.0f : 0.0f;
    }
  }
}

extern "C" void kernel_launch(void* const* d_in, const int* in_sizes, int n_in,
                              void* d_out, int out_size, void* d_ws, size_t ws_size,
                              hipStream_t stream) {
  const float* img   = (const float*)d_in[0];
  const float* randu = (const float*)d_in[1];
  const float* W1    = (const float*)d_in[2];
  const float* W2    = (const float*)d_in[3];
  float* out = (float*)d_out;

  char* ws = (char*)d_ws;
  size_t off = 0;
  auto alloc = [&](size_t bytes) -> void* {
    void* p = ws + off;
    off = (off + bytes + 511) & ~(size_t)511;
    return p;
  };
  uint8_t*  s0b = (uint8_t*) alloc((size_t)N_B * TT * NK);                      // 31.9 MB
  v4i*      Bf  = (v4i*)     alloc((size_t)NDIG * NTILES * NKS * 64 * 16);      // 1.4 MB
  v4i*      Bf2 = (v4i*)     alloc((size_t)NDIG * NKS2 * 64 * 16);              // 28 KB
  uint8_t*  s1  = (uint8_t*) alloc((size_t)N_B * S1_NSTRIDE);                   // 17.2 MB
  if (off > ws_size) return;

  k_pack    <<<dim3(5, NKS, N_B), 64, 0, stream>>>(randu, img, s0b);
  k_bprepall<<<dim3(NDIG * NTILES * NKS + NDIG * NKS2), 64, 0, stream>>>(W1, W2, Bf, Bf2);
  k_fused2  <<<dim3(NWG1), 256, 0, stream>>>(s0b, Bf, s1);
  k_l2f     <<<dim3(2, N_B), 256, 0, stream>>>(s1, Bf2, out);
}